// Round 14
// baseline (274.358 us; speedup 1.0000x reference)
//
#include <hip/hip_runtime.h>
#include <math.h>

// QSAR fused pipeline, ONE BLOCK OF 512 THREADS PER MOLECULE.
// B=4096, A=64, D=6, AF=37, BF=6, H=128.
// R14 = R13 (dedup, 266us) + k-split widening of the two serial GEMV chains:
//  - conv2: wave-per-atom, k halved across wave halves (shfl_xor(32) reduce). 134->67.
//  - P5a:   wave-per-unique-row, same split. 128->64, 7/8 waves active.
// R13's dedup kept: x2p rows with equal work-member masks are identical (~7 unique);
// dedup scan in wave-0 registers; P4 pools unique rows only; P5b scatters
// logits[a] = dense[rep(a)] + bo + bsum.Wotail (tail loads loop-invariant -> hoisted).
// Envelope: (512,8), LDS 40448B -> 4 blocks/CU. Spill tripwire: WRITE_SIZE ~128KB.

__device__ __forceinline__ float4 max4(float4 a, float4 b) {
  return make_float4(fmaxf(a.x, b.x), fmaxf(a.y, b.y), fmaxf(a.z, b.z), fmaxf(a.w, b.w));
}

__device__ __forceinline__ float4 nbr_max(const float4* sx4, const int* se, int a, int c4) {
  float4 m = sx4[a * 32 + c4];
#pragma unroll
  for (int d = 0; d < 6; ++d) {
    int e = se[a * 6 + d];
    if (e >= 0) m = max4(m, sx4[e * 32 + c4]);
  }
  return m;
}

__device__ __forceinline__ float4 nbr_sum(const float4* sx4, const int* se, int a, int c4) {
  float4 s = sx4[a * 32 + c4];
#pragma unroll
  for (int d = 0; d < 6; ++d) {
    int e = se[a * 6 + d];
    if (e >= 0) {
      float4 v = sx4[e * 32 + c4];
      s.x += v.x; s.y += v.y; s.z += v.z; s.w += v.w;
    }
  }
  return s;
}

// pool2: max over WORK members only; non-work x2 rows implicitly 0, relu>=0 -> 0-init exact.
__device__ __forceinline__ float4 nbr_wmax(const float4* sx4, const int* se, const int* sdeg,
                                           int a, int c4) {
  float4 m = make_float4(0.f, 0.f, 0.f, 0.f);
  if (sdeg[a] < 6) m = max4(m, sx4[a * 32 + c4]);
#pragma unroll
  for (int d = 0; d < 6; ++d) {
    int e = se[a * 6 + d];
    if (e >= 0 && sdeg[e] < 6) m = max4(m, sx4[e * 32 + c4]);
  }
  return m;
}

__global__ __launch_bounds__(512, 8) void qsar_fused(
    const float* __restrict__ atoms, const float* __restrict__ bonds,
    const int* __restrict__ edges,
    const float* __restrict__ W1, const float* __restrict__ b1,
    const float* __restrict__ W2, const float* __restrict__ b2,
    const float* __restrict__ Wo, const float* __restrict__ bo,
    const float* __restrict__ Wm1, const float* __restrict__ bm1,
    const float* __restrict__ Wm2, const float* __restrict__ bm2,
    const float* __restrict__ Wm3, const float* __restrict__ bm3,
    float* __restrict__ out)
{
  const int b    = blockIdx.x;
  const int tid  = threadIdx.x;        // 0..511
  const int hid  = tid >> 5;           // half-wave unit id 0..15
  const int hl   = tid & 31;           // lane in half-wave
  const int wv   = tid >> 6;           // wave id 0..7
  const int ln   = tid & 63;           // lane in wave

  __shared__ float s_x[64 * 128];      // 32768 B
  __shared__ float s_sa[608];          // conv1 gather 16x38; later fp(512)+h1(64)+h2(32)
  __shared__ float s_bsum[64 * 8];     // 2048 B
  __shared__ int   s_edges[64 * 6];    // 1536 B
  __shared__ int   s_deg[64];
  __shared__ int   s_work[64];         // deg<6 atoms
  __shared__ int   s_urow[64];         // unique-row id per atom, -1 if zero x2p row
  __shared__ int   s_uniq[64];         // atom id of each unique row
  __shared__ float s_rsum[64];
  __shared__ int   s_nwork, s_nu;

  float4* sx4  = reinterpret_cast<float4*>(s_x);
  float*  s_fp = s_sa;                 // 512 floats (4 partials x 128)
  float*  s_h1 = s_sa + 512;           // 64
  float*  s_h2 = s_sa + 576;           // 32

  // ---------------- P0: stage edges, bsum; zero s_x; reset counters -------------------
  {
    const int* ge = edges + (size_t)b * (64 * 6);
    for (int i = tid; i < 64 * 6; i += 512) s_edges[i] = ge[i];
    const float* gb = bonds + (size_t)b * (64 * 36);
    for (int i = tid; i < 64 * 6; i += 512) {
      int a = i / 6, f = i - a * 6;
      float s = 0.f;
#pragma unroll
      for (int d = 0; d < 6; ++d) s += gb[a * 36 + d * 6 + f];
      s_bsum[a * 8 + f] = s;
    }
#pragma unroll
    for (int j = 0; j < 4; ++j) sx4[tid + j * 512] = make_float4(0.f, 0.f, 0.f, 0.f);
    if (tid == 0) { s_nwork = 0; s_nu = 0; }
  }
  __syncthreads();

  // ---------------- P0b: degree + worklist --------------------------------------------
  if (tid < 64) {
    int dcnt = 0;
#pragma unroll
    for (int d = 0; d < 6; ++d) dcnt += (s_edges[tid * 6 + d] >= 0) ? 1 : 0;
    s_deg[tid] = dcnt;
    if (dcnt < 6) { int p = atomicAdd(&s_nwork, 1); s_work[p] = tid; }
  }
  __syncthreads();

  // ---------------- P0c: x2p dedup in wave-0 registers (shfl scan) --------------------
  if (tid < 64) {
    unsigned int mlo = 0u, mhi = 0u;
    if (s_deg[tid] < 6) { if (tid < 32) mlo |= 1u << tid; else mhi |= 1u << (tid - 32); }
#pragma unroll
    for (int d = 0; d < 6; ++d) {
      int e = s_edges[tid * 6 + d];
      if (e >= 0 && s_deg[e] < 6) { if (e < 32) mlo |= 1u << e; else mhi |= 1u << (e - 32); }
    }
    const bool nz = (mlo | mhi) != 0u;
    int rep = tid;
    for (int bb = 0; bb < 64; ++bb) {
      const unsigned int blo = (unsigned int)__shfl((int)mlo, bb);
      const unsigned int bhi = (unsigned int)__shfl((int)mhi, bb);
      if (bb < tid && blo == mlo && bhi == mhi && rep == tid) rep = bb;
    }
    int u = -1;
    if (nz && rep == tid) u = atomicAdd(&s_nu, 1);
    const int urep = __shfl(u, rep);
    s_urow[tid] = nz ? urep : -1;
    if (u >= 0) s_uniq[u] = tid;
  }
  // (visible after the next barrier inside P1)

  // ---------------- P1: conv1, 16 half-wave GEMV units, chunks of <=16 work atoms -----
  {
    const int nw = s_nwork;
    const float* ga = atoms + (size_t)b * (64 * 37);
    const int c0 = hl * 4;
    for (int cb = 0; cb < nw; cb += 16) {
      const int cnt = (nw - cb < 16) ? (nw - cb) : 16;
      for (int i = tid; i < cnt * 37; i += 512) {
        int wi = i / 37, k = i - wi * 37;
        int a = s_work[cb + wi];
        float f = ga[a * 37 + k];
#pragma unroll
        for (int d = 0; d < 6; ++d) {
          int e = s_edges[a * 6 + d];
          if (e >= 0) f += ga[e * 37 + k];
        }
        s_sa[wi * 38 + k] = f;
      }
      __syncthreads();
      for (int w = hid; w < cnt; w += 16) {
        const int a = s_work[cb + w];
        const int d = s_deg[a];
        const float4* wdf4 = reinterpret_cast<const float4*>(W1 + d * (43 * 128));
        float4 acc = *reinterpret_cast<const float4*>(&b1[d * 128 + c0]);
#pragma unroll 4
        for (int k = 0; k < 37; ++k) {
          const float ff = s_sa[w * 38 + k];
          const float4 w4 = wdf4[k * 32 + hl];
          acc.x = fmaf(ff, w4.x, acc.x); acc.y = fmaf(ff, w4.y, acc.y);
          acc.z = fmaf(ff, w4.z, acc.z); acc.w = fmaf(ff, w4.w, acc.w);
        }
#pragma unroll
        for (int kk = 0; kk < 6; ++kk) {
          const float ff = s_bsum[a * 8 + kk];
          const float4 w4 = wdf4[(37 + kk) * 32 + hl];
          acc.x = fmaf(ff, w4.x, acc.x); acc.y = fmaf(ff, w4.y, acc.y);
          acc.z = fmaf(ff, w4.z, acc.z); acc.w = fmaf(ff, w4.w, acc.w);
        }
        *reinterpret_cast<float4*>(&s_x[a * 128 + c0]) =
            make_float4(fmaxf(acc.x, 0.f), fmaxf(acc.y, 0.f),
                        fmaxf(acc.z, 0.f), fmaxf(acc.w, 0.f));
      }
      __syncthreads();
    }
  }
  __syncthreads();

  // ---------------- P2: pool1 in place (all rows), float4, 4 elems/thread -------------
  {
    float4 v0 = nbr_max(sx4, s_edges, (tid + 0 * 512) >> 5, tid & 31);
    float4 v1 = nbr_max(sx4, s_edges, (tid + 1 * 512) >> 5, tid & 31);
    float4 v2 = nbr_max(sx4, s_edges, (tid + 2 * 512) >> 5, tid & 31);
    float4 v3 = nbr_max(sx4, s_edges, (tid + 3 * 512) >> 5, tid & 31);
    __syncthreads();
    sx4[tid + 0 * 512] = v0; sx4[tid + 1 * 512] = v1;
    sx4[tid + 2 * 512] = v2; sx4[tid + 3 * 512] = v3;
  }
  __syncthreads();

  // ---------------- P2b: ysum for work rows in place ----------------------------------
  {
    const float4 z = make_float4(0.f, 0.f, 0.f, 0.f);
    float4 v0 = z, v1 = z, v2 = z, v3 = z;
    if (s_deg[(tid + 0 * 512) >> 5] < 6) v0 = nbr_sum(sx4, s_edges, (tid + 0 * 512) >> 5, tid & 31);
    if (s_deg[(tid + 1 * 512) >> 5] < 6) v1 = nbr_sum(sx4, s_edges, (tid + 1 * 512) >> 5, tid & 31);
    if (s_deg[(tid + 2 * 512) >> 5] < 6) v2 = nbr_sum(sx4, s_edges, (tid + 2 * 512) >> 5, tid & 31);
    if (s_deg[(tid + 3 * 512) >> 5] < 6) v3 = nbr_sum(sx4, s_edges, (tid + 3 * 512) >> 5, tid & 31);
    __syncthreads();
    if (s_deg[(tid + 0 * 512) >> 5] < 6) sx4[tid + 0 * 512] = v0;
    if (s_deg[(tid + 1 * 512) >> 5] < 6) sx4[tid + 1 * 512] = v1;
    if (s_deg[(tid + 2 * 512) >> 5] < 6) sx4[tid + 2 * 512] = v2;
    if (s_deg[(tid + 3 * 512) >> 5] < 6) sx4[tid + 3 * 512] = v3;
  }
  __syncthreads();

  // ---------------- P3: conv2, wave-per-atom, k halved across wave halves -------------
  // ch=ln>>5: ch0 takes k<64 + bsum 0..2 (+bias), ch1 takes k>=64 + bsum 3..5.
  // All reads of row a precede the shfl (data dep) which precedes the write (program
  // order, same wave). Rows across waves disjoint -> no internal barriers.
  {
    const int nw = s_nwork;
    const int ch = ln >> 5;
    const int c0 = (ln & 31) * 4;
    for (int w = wv; w < nw; w += 8) {
      const int a = s_work[w];
      const int d = s_deg[a];
      const float4* wdf4 = reinterpret_cast<const float4*>(W2 + d * (134 * 128));
      float4 acc = make_float4(0.f, 0.f, 0.f, 0.f);
      if (ch == 0) acc = *reinterpret_cast<const float4*>(&b2[d * 128 + c0]);
      const int kb = ch * 64;
#pragma unroll 4
      for (int j = 0; j < 64; ++j) {
        const float ff = s_x[a * 128 + kb + j];
        const float4 w4 = wdf4[(kb + j) * 32 + (ln & 31)];
        acc.x = fmaf(ff, w4.x, acc.x); acc.y = fmaf(ff, w4.y, acc.y);
        acc.z = fmaf(ff, w4.z, acc.z); acc.w = fmaf(ff, w4.w, acc.w);
      }
#pragma unroll
      for (int t = 0; t < 3; ++t) {
        const int kk = ch * 3 + t;
        const float ff = s_bsum[a * 8 + kk];
        const float4 w4 = wdf4[(128 + kk) * 32 + (ln & 31)];
        acc.x = fmaf(ff, w4.x, acc.x); acc.y = fmaf(ff, w4.y, acc.y);
        acc.z = fmaf(ff, w4.z, acc.z); acc.w = fmaf(ff, w4.w, acc.w);
      }
      acc.x += __shfl_xor(acc.x, 32); acc.y += __shfl_xor(acc.y, 32);
      acc.z += __shfl_xor(acc.z, 32); acc.w += __shfl_xor(acc.w, 32);
      if (ch == 0)
        *reinterpret_cast<float4*>(&s_x[a * 128 + c0]) =
            make_float4(fmaxf(acc.x, 0.f), fmaxf(acc.y, 0.f),
                        fmaxf(acc.z, 0.f), fmaxf(acc.w, 0.f));
    }
  }
  __syncthreads();

  // ---------------- P4: pool2 for UNIQUE rows only (register-stage + scatter) ---------
  {
    const int lim = s_nu * 32;          // float4 slots
    const float4 z = make_float4(0.f, 0.f, 0.f, 0.f);
    float4 v0 = z, v1 = z, v2 = z, v3 = z;
    const int i0 = tid, i1 = tid + 512, i2 = tid + 1024, i3 = tid + 1536;
    if (i0 < lim) v0 = nbr_wmax(sx4, s_edges, s_deg, s_uniq[i0 >> 5], i0 & 31);
    if (i1 < lim) v1 = nbr_wmax(sx4, s_edges, s_deg, s_uniq[i1 >> 5], i1 & 31);
    if (i2 < lim) v2 = nbr_wmax(sx4, s_edges, s_deg, s_uniq[i2 >> 5], i2 & 31);
    if (i3 < lim) v3 = nbr_wmax(sx4, s_edges, s_deg, s_uniq[i3 >> 5], i3 & 31);
    __syncthreads();
    if (i0 < lim) sx4[s_uniq[i0 >> 5] * 32 + (i0 & 31)] = v0;
    if (i1 < lim) sx4[s_uniq[i1 >> 5] * 32 + (i1 & 31)] = v1;
    if (i2 < lim) sx4[s_uniq[i2 >> 5] * 32 + (i2 & 31)] = v2;
    if (i3 < lim) sx4[s_uniq[i3 >> 5] * 32 + (i3 & 31)] = v3;
  }
  __syncthreads();

  // ---------------- P5a: dense GEMV per unique row, wave-per-row, k halved ------------
  // Same split as P3: ch0 k<64, ch1 k>=64; shfl_xor(32) reduce; ch0 lanes write the
  // DENSE dot only (bias/tail added in P5b). In-place row write is same-wave-safe.
  {
    const int nu = s_nu;
    const int ch = ln >> 5;
    const int c0 = (ln & 31) * 4;
    const float4* Wof4 = reinterpret_cast<const float4*>(Wo);
    for (int w = wv; w < nu; w += 8) {
      const int arow = s_uniq[w] * 128;
      float4 acc = make_float4(0.f, 0.f, 0.f, 0.f);
      const int kb = ch * 64;
#pragma unroll 4
      for (int j = 0; j < 64; ++j) {
        const float ff = s_x[arow + kb + j];
        const float4 w4 = Wof4[(kb + j) * 32 + (ln & 31)];
        acc.x = fmaf(ff, w4.x, acc.x); acc.y = fmaf(ff, w4.y, acc.y);
        acc.z = fmaf(ff, w4.z, acc.z); acc.w = fmaf(ff, w4.w, acc.w);
      }
      acc.x += __shfl_xor(acc.x, 32); acc.y += __shfl_xor(acc.y, 32);
      acc.z += __shfl_xor(acc.z, 32); acc.w += __shfl_xor(acc.w, 32);
      if (ch == 0)
        *reinterpret_cast<float4*>(&s_x[arow + c0]) = acc;
    }
  }
  __syncthreads();

  // ---------------- P5b: scatter logits[a] = dense[rep(a)] + bo + bsum.Wotail ---------
  // c = tid&127 is fixed per thread -> the 6 Wo-tail loads + bo are loop-invariant
  // (compiler-hoisted). Stage 16 values, barrier, write.
  {
    float st[16];
#pragma unroll
    for (int j = 0; j < 16; ++j) {
      const int e = tid + j * 512;
      const int a = e >> 7, c = e & 127;
      const int ur = s_urow[a];
      float acc = bo[c];
#pragma unroll
      for (int kk = 0; kk < 6; ++kk)
        acc = fmaf(s_bsum[a * 8 + kk], Wo[(128 + kk) * 128 + c], acc);
      if (ur >= 0) acc += s_x[s_uniq[ur] * 128 + c];
      st[j] = acc;
    }
    __syncthreads();
#pragma unroll
    for (int j = 0; j < 16; ++j) s_x[tid + j * 512] = st[j];
  }
  __syncthreads();

  // ---------------- P6: per-atom softmax over 128, 8 lanes/atom, in registers ---------
  {
    const int a = tid >> 3, q = tid & 7;     // 64 atoms x 8 lanes
    float* base = &s_x[a * 128 + q * 16];
    const float4 v0 = *reinterpret_cast<const float4*>(base + ((0 + tid) & 3) * 4);
    const float4 v1 = *reinterpret_cast<const float4*>(base + ((1 + tid) & 3) * 4);
    const float4 v2 = *reinterpret_cast<const float4*>(base + ((2 + tid) & 3) * 4);
    const float4 v3 = *reinterpret_cast<const float4*>(base + ((3 + tid) & 3) * 4);
    float mx = fmaxf(fmaxf(fmaxf(v0.x, v0.y), fmaxf(v0.z, v0.w)),
                     fmaxf(fmaxf(v1.x, v1.y), fmaxf(v1.z, v1.w)));
    mx = fmaxf(mx, fmaxf(fmaxf(fmaxf(v2.x, v2.y), fmaxf(v2.z, v2.w)),
                         fmaxf(fmaxf(v3.x, v3.y), fmaxf(v3.z, v3.w))));
    mx = fmaxf(mx, __shfl_xor(mx, 1));
    mx = fmaxf(mx, __shfl_xor(mx, 2));
    mx = fmaxf(mx, __shfl_xor(mx, 4));
    float4 e0, e1, e2, e3;
    e0.x = __expf(v0.x - mx); e0.y = __expf(v0.y - mx); e0.z = __expf(v0.z - mx); e0.w = __expf(v0.w - mx);
    e1.x = __expf(v1.x - mx); e1.y = __expf(v1.y - mx); e1.z = __expf(v1.z - mx); e1.w = __expf(v1.w - mx);
    e2.x = __expf(v2.x - mx); e2.y = __expf(v2.y - mx); e2.z = __expf(v2.z - mx); e2.w = __expf(v2.w - mx);
    e3.x = __expf(v3.x - mx); e3.y = __expf(v3.y - mx); e3.z = __expf(v3.z - mx); e3.w = __expf(v3.w - mx);
    float sm = e0.x + e0.y + e0.z + e0.w;
    sm += e1.x + e1.y + e1.z + e1.w;
    sm += e2.x + e2.y + e2.z + e2.w;
    sm += e3.x + e3.y + e3.z + e3.w;
    *reinterpret_cast<float4*>(base + ((0 + tid) & 3) * 4) = e0;
    *reinterpret_cast<float4*>(base + ((1 + tid) & 3) * 4) = e1;
    *reinterpret_cast<float4*>(base + ((2 + tid) & 3) * 4) = e2;
    *reinterpret_cast<float4*>(base + ((3 + tid) & 3) * 4) = e3;
    sm += __shfl_xor(sm, 1);
    sm += __shfl_xor(sm, 2);
    sm += __shfl_xor(sm, 4);
    if (q == 0) s_rsum[a] = (s_deg[a] != 0) ? (1.f / sm) : 0.f;
  }
  __syncthreads();

  // ---------------- P7: fingerprint (4 partials x 128, aliases dead s_sa) -------------
  {
    const int c = tid & 127, quarter = tid >> 7;   // 0..3
    float s = 0.f;
    for (int a2 = quarter * 16; a2 < quarter * 16 + 16; ++a2)
      s = fmaf(s_x[a2 * 128 + c], s_rsum[a2], s);
    s_fp[quarter * 128 + c] = s;
  }
  __syncthreads();
  if (tid < 128) s_fp[tid] += s_fp[128 + tid] + s_fp[256 + tid] + s_fp[384 + tid];
  __syncthreads();

  // ---------------- P8: MLP head ------------------------------------------------------
  if (tid < 64) {
    float acc = bm1[tid];
    for (int k = 0; k < 128; ++k) acc = fmaf(s_fp[k], Wm1[k * 64 + tid], acc);
    s_h1[tid] = fmaxf(acc, 0.f);
  }
  __syncthreads();
  if (tid < 32) {
    float acc = bm2[tid];
    for (int k = 0; k < 64; ++k) acc = fmaf(s_h1[k], Wm2[k * 32 + tid], acc);
    s_h2[tid] = fmaxf(acc, 0.f);
  }
  __syncthreads();
  if (tid < 64) {
    float p = (tid < 32) ? s_h2[tid] * Wm3[tid] : 0.f;
#pragma unroll
    for (int off = 32; off > 0; off >>= 1) p += __shfl_xor(p, off);
    if (tid == 0) out[b] = p + bm3[0];
  }
}

extern "C" void kernel_launch(void* const* d_in, const int* in_sizes, int n_in,
                              void* d_out, int out_size, void* d_ws, size_t ws_size,
                              hipStream_t stream) {
  const float* atoms = (const float*)d_in[0];
  const float* bonds = (const float*)d_in[1];
  const int*   edges = (const int*)d_in[2];
  const float* W1  = (const float*)d_in[3];
  const float* b1  = (const float*)d_in[4];
  const float* W2  = (const float*)d_in[5];
  const float* b2  = (const float*)d_in[6];
  const float* Wo  = (const float*)d_in[7];
  const float* bo  = (const float*)d_in[8];
  const float* Wm1 = (const float*)d_in[9];
  const float* bm1 = (const float*)d_in[10];
  const float* Wm2 = (const float*)d_in[11];
  const float* bm2 = (const float*)d_in[12];
  const float* Wm3 = (const float*)d_in[13];
  const float* bm3 = (const float*)d_in[14];
  float* out = (float*)d_out;

  const int B = out_size;  // 4096 molecules
  qsar_fused<<<dim3(B), dim3(512), 0, stream>>>(
      atoms, bonds, edges, W1, b1, W2, b2, Wo, bo,
      Wm1, bm1, Wm2, bm2, Wm3, bm3, out);
}